// Round 2
// baseline (2717.568 us; speedup 1.0000x reference)
//
#include <hip/hip_runtime.h>
#include <cfloat>

// Problem constants (B=16,S=4096,H=512,G=2,V=320,D=128)
#define MTOT 65536
#define KH   512
#define GD   256
#define NG   2
#define ND   128
#define NV   320

// d_out float offsets: quantized [16,4096,256], encodings [2,16,4096,320],
// distances [2,16,4096,320], perplexity scalar
#define Q_OFF    0ull
#define ENC_OFF  16777216ull
#define DIST_OFF 58720256ull
#define PERP_OFF 100663296ull

// h buffer lives inside the encodings-g0 region (fully overwritten at the end
// of dist_kernel): row layout stride 320: [0..255]=h, [256]=h2_g0, [257]=h2_g1.

// ---------------- Kernel A: h = X@W + b, h2 ----------------
// lane = output col (256 cols / 4 waves), 64 rows per block.
// W per-lane coalesced global loads; X wave-uniform -> s_load streams.
__global__ __launch_bounds__(256) void proj_kernel(
    const float* __restrict__ X, const float* __restrict__ W,
    const float* __restrict__ bias, float* __restrict__ hbuf) {
  __shared__ float h2p[4][64];
  const int t    = threadIdx.x;
  const int lane = t & 63;
  const int wv   = __builtin_amdgcn_readfirstlane(t >> 6); // 0..3
  const int col  = (wv << 6) | lane;                       // 0..255
  const int row0 = blockIdx.x << 6;

  float acc[64];
#pragma unroll
  for (int r = 0; r < 64; ++r) acc[r] = 0.f;

  for (int kc = 0; kc < 16; ++kc) {  // K chunks of 32
    float wf[32];
#pragma unroll
    for (int k = 0; k < 32; ++k) wf[k] = W[(size_t)(kc * 32 + k) * GD + col];
    const float* xbase = X + (size_t)row0 * KH + kc * 32;
    float xa[32], xb[32];
#pragma unroll
    for (int k = 0; k < 32; ++k) xa[k] = xbase[k];  // row 0 (uniform -> s_load)
#pragma unroll
    for (int r = 0; r < 64; r += 2) {
      const float* nx1 = xbase + (size_t)(r + 1) * KH;
#pragma unroll
      for (int k = 0; k < 32; ++k) xb[k] = nx1[k];
#pragma unroll
      for (int k = 0; k < 32; ++k) acc[r] = fmaf(xa[k], wf[k], acc[r]);
      const float* nx2 = xbase + (size_t)(r + 2 < 64 ? r + 2 : r + 1) * KH;
#pragma unroll
      for (int k = 0; k < 32; ++k) xa[k] = nx2[k];
#pragma unroll
      for (int k = 0; k < 32; ++k) acc[r + 1] = fmaf(xb[k], wf[k], acc[r + 1]);
    }
  }

  // epilogue: bias, store h (coalesced), per-row h2 via wave reduce
  const float vb = bias[col];
  float* hrow = hbuf + (size_t)row0 * 320;
#pragma unroll
  for (int r = 0; r < 64; ++r) {
    float h = acc[r] + vb;
    hrow[(size_t)r * 320 + col] = h;
    float sq = h * h;
#pragma unroll
    for (int off = 1; off < 64; off <<= 1) sq += __shfl_xor(sq, off);
    if (lane == 0) h2p[wv][r] = sq;
  }
  __syncthreads();
  if (t < 64) {
    hrow[(size_t)t * 320 + 256] = h2p[0][t] + h2p[1][t];  // h2 group 0
    hrow[(size_t)t * 320 + 257] = h2p[2][t] + h2p[3][t];  // h2 group 1
  }
}

// ---------------- Kernel B: distances/argmin/enc/quant ----------------
// lane = row (64 rows/block); h fragment per-lane in VGPRs (via LDS stage);
// codevectors wave-uniform -> s_load streams; dist bounced through padded LDS
// tile for coalesced global stores.
__global__ __launch_bounds__(256) void dist_kernel(
    const float* __restrict__ C, const float* __restrict__ hbuf,
    float* __restrict__ out, int* __restrict__ hist) {
  __shared__ float smem[10400];   // union: hl[64*132=8448] | dt[160*65=10400]
  __shared__ float c2l[640];
  __shared__ float pmin[64][8];
  __shared__ int   pidx[64][8];
  __shared__ int   idxbuf[2][64];
  const int t    = threadIdx.x;
  const int lane = t & 63;
  const int wv   = __builtin_amdgcn_readfirstlane(t >> 6); // 0..3
  const int row0 = blockIdx.x << 6;

  // c2 into LDS (per block; C is L2-hot, ~tiny cost)
  for (int p = 0; p < 3; ++p) {
    int gv = t + 256 * p;
    if (gv < 640) {
      const float* cp = C + (size_t)gv * ND;
      float s = 0.f;
#pragma unroll
      for (int q = 0; q < 32; ++q) {
        float4 v = *(const float4*)(cp + 4 * q);
        s = fmaf(v.x, v.x, s); s = fmaf(v.y, v.y, s);
        s = fmaf(v.z, v.z, s); s = fmaf(v.w, v.w, s);
      }
      c2l[gv] = s;
    }
  }

  for (int g = 0; g < NG; ++g) {
    __syncthreads();  // hl region free (aliases dt of prev group); c2l ready
    // stage hl[r][d] (stride 132) from hbuf
#pragma unroll
    for (int p = 0; p < 8; ++p) {
      int flat = t + 256 * p;  // quad index 0..2047
      int r = flat >> 5, dq = flat & 31;
      float4 v = *(const float4*)(hbuf + (size_t)(row0 + r) * 320 + g * ND + 4 * dq);
      *(float4*)(smem + 132 * r + 4 * dq) = v;
    }
    __syncthreads();
    // h fragment: this lane's row, all 128 d
    float hf[128];
#pragma unroll
    for (int dq = 0; dq < 32; ++dq)
      *(float4*)(hf + 4 * dq) = *(const float4*)(smem + 132 * lane + 4 * dq);
    const float vh2 = hbuf[(size_t)(row0 + lane) * 320 + 256 + g];
    __syncthreads();  // hl consumed -> dt region writable

    for (int pass = 0; pass < 2; ++pass) {
      const int cb = 160 * pass + 40 * wv;  // this wave's first col
      const float* cgrp = C + (size_t)g * NV * ND;
      float ca[32], cbuf[32];
      {
        const float* cp0 = cgrp + (size_t)cb * ND;
#pragma unroll
        for (int k = 0; k < 32; ++k) ca[k] = cp0[k];  // uniform -> s_load
      }
      for (int cc = 0; cc < 40; ++cc) {
        const int colg = cb + cc;
        const float* cp  = cgrp + (size_t)colg * ND;
        const float* cpn = cgrp + (size_t)(cc + 1 < 40 ? colg + 1 : colg) * ND;
        float acc = 0.f;
#pragma unroll
        for (int k = 0; k < 32; ++k) cbuf[k] = cp[32 + k];
#pragma unroll
        for (int k = 0; k < 32; ++k) acc = fmaf(hf[k], ca[k], acc);
#pragma unroll
        for (int k = 0; k < 32; ++k) ca[k] = cp[64 + k];
#pragma unroll
        for (int k = 0; k < 32; ++k) acc = fmaf(hf[32 + k], cbuf[k], acc);
#pragma unroll
        for (int k = 0; k < 32; ++k) cbuf[k] = cp[96 + k];
#pragma unroll
        for (int k = 0; k < 32; ++k) acc = fmaf(hf[64 + k], ca[k], acc);
#pragma unroll
        for (int k = 0; k < 32; ++k) ca[k] = cpn[k];  // prefetch next col chunk0
#pragma unroll
        for (int k = 0; k < 32; ++k) acc = fmaf(hf[96 + k], cbuf[k], acc);
        const float c2v = c2l[g * NV + colg];
        const float d = fmaf(acc, -2.f, vh2 + c2v);
        smem[65 * (40 * wv + cc) + lane] = d;  // dt[local col][row], pad 65
      }
      __syncthreads();
      // coalesced dist stores
#pragma unroll
      for (int q = 0; q < 8; ++q)
#pragma unroll
        for (int s = 0; s < 5; ++s) {
          int row = 8 * q + (t >> 5);
          int cl  = 32 * s + (t & 31);
          float d = smem[65 * cl + row];
          out[DIST_OFF + ((size_t)g * MTOT + row0 + row) * NV + 160 * pass + cl] = d;
        }
      // argmin partial scan (tie -> lower col: strict <, ascending cols)
      {
        int row = t >> 2, part = t & 3;
        float mv = FLT_MAX; int mi = 0;
        for (int j = 0; j < 40; ++j) {
          int cl = part * 40 + j;
          float d = smem[65 * cl + row];
          if (d < mv) { mv = d; mi = 160 * pass + cl; }
        }
        pmin[row][4 * pass + part] = mv;
        pidx[row][4 * pass + part] = mi;
      }
      __syncthreads();
    }
    // combine partials (slots in ascending col order)
    if (t < 64) {
      float mv = FLT_MAX; int mi = 0;
#pragma unroll
      for (int s = 0; s < 8; ++s) {
        float v = pmin[t][s];
        if (v < mv) { mv = v; mi = pidx[t][s]; }
      }
      idxbuf[g][t] = mi;
      atomicAdd(&hist[g * NV + mi], 1);
    }
  }
  __syncthreads();
  // encodings (full rows; overwrites the h scratch region for g=0)
  for (int g = 0; g < NG; ++g) {
#pragma unroll
    for (int q = 0; q < 16; ++q)
#pragma unroll
      for (int s = 0; s < 5; ++s) {
        int row = 4 * q + wv;         // wave-uniform row
        int col = 64 * s + lane;
        float v = (col == idxbuf[g][row]) ? 1.f : 0.f;
        out[ENC_OFF + ((size_t)g * MTOT + row0 + row) * NV + col] = v;
      }
  }
  // quantized features (gather selected codevectors, L2-hot)
  for (int g = 0; g < NG; ++g) {
#pragma unroll
    for (int q = 0; q < 8; ++q)
#pragma unroll
      for (int s = 0; s < 4; ++s) {
        int row = 8 * q + (t >> 5);
        int d   = 32 * s + (t & 31);
        int idx = idxbuf[g][row];
        float v = C[((size_t)g * NV + idx) * ND + d];
        out[Q_OFF + (size_t)(row0 + row) * GD + g * ND + d] = v;
      }
  }
}

// ---------------- perplexity ----------------
__global__ void perp_kernel(const int* __restrict__ hist, float* __restrict__ outp) {
  int t = threadIdx.x;  // 1 wave
  float s0 = 0.f, s1 = 0.f;
  for (int v = t; v < NV; v += 64) {
    float p0 = fminf(fmaxf((float)hist[v] * (1.0f / 65536.f), 1e-10f), 1.0f);
    float p1 = fminf(fmaxf((float)hist[NV + v] * (1.0f / 65536.f), 1e-10f), 1.0f);
    s0 += p0 * logf(p0 + 1e-10f);
    s1 += p1 * logf(p1 + 1e-10f);
  }
#pragma unroll
  for (int off = 1; off < 64; off <<= 1) {
    s0 += __shfl_xor(s0, off);
    s1 += __shfl_xor(s1, off);
  }
  if (t == 0) outp[0] = 0.5f * (expf(-s0) + expf(-s1));
}

extern "C" void kernel_launch(void* const* d_in, const int* in_sizes, int n_in,
                              void* d_out, int out_size, void* d_ws, size_t ws_size,
                              hipStream_t stream) {
  const float* X    = (const float*)d_in[0];
  const float* W    = (const float*)d_in[1];
  const float* bias = (const float*)d_in[2];
  const float* C    = (const float*)d_in[3];
  float* out = (float*)d_out;
  int* hist = (int*)d_ws;  // [2,320] ints = 2560 B

  hipMemsetAsync(d_ws, 0, 2560, stream);
  proj_kernel<<<1024, 256, 0, stream>>>(X, W, bias, out + ENC_OFF);
  dist_kernel<<<1024, 256, 0, stream>>>(C, out + ENC_OFF, out, hist);
  perp_kernel<<<1, 64, 0, stream>>>(hist, out + PERP_OFF);
}